// Round 3
// baseline (369.779 us; speedup 1.0000x reference)
//
#include <hip/hip_runtime.h>

// BatchedCauchyKernel3d: out[b,i,j] = 1 / (1 + d/sqrt(scx[b,i]*scy[b,j]))
// d = clip(|x_i|^2 + |y_j|^2 - 2 x_i.y_j, 1e-10, 1e6)
// scx = clip(sample_x . clip(scale,1e-6,1e6), 1e-10, 1e6); likewise scy.
// Identities:
//   1/(1+d/s) == s/(s+d)                       -> one rcp per element
//   sqrt(clip(scx*scy,1e-10,1e12)) == max(sqrt(scx)*sqrt(scy), 1e-5)
//     (upper clip vacuous: sqrt(scx),sqrt(scy) <= 1e3)
// Single fused kernel (R2): stats recomputed per block (sx/sy are 2 MB total,
// L2-resident; redundancy ~19 extra L2-hit loads/thread) — removes the
// pre-pass dispatch + graph gap. Bijective XCD-chunk swizzle so each XCD
// streams a contiguous 33.5 MB output region. Plain (non-NT) float4 stores.

constexpr int kB  = 4;
constexpr int kNX = 4096;
constexpr int kNY = 4096;
constexpr int kF  = 16;
constexpr int kNumXCD = 8;

__global__ __launch_bounds__(256) void cauchy_fused_kernel(
    const float* __restrict__ x, const float* __restrict__ y,
    const float* __restrict__ sx, const float* __restrict__ sy,
    const float* __restrict__ scale, float* __restrict__ out)
{
    constexpr int kNBlk = (kB * kNX * kNY / 16) / 256;   // 16384, %8 == 0
    // hw block n -> XCD n%8 (round-robin). Give XCD k the contiguous logical
    // range [k*kNBlk/8, (k+1)*kNBlk/8): per-XCD output writes are a single
    // contiguous stream. Bijective since kNBlk % kNumXCD == 0.
    const int hw = blockIdx.x;
    const int logical = (hw % kNumXCD) * (kNBlk / kNumXCD) + hw / kNumXCD;

    const int jc = ((logical & 3) << 8) | threadIdx.x;   // 0..1023
    const int rowtile = logical >> 2;                    // block-uniform
    const int b  = rowtile >> 10;
    const int i0 = (rowtile & (kNX / 4 - 1)) << 2;
    const int j0 = jc << 2;

    // clipped scale vector (uniform)
    float4 c[4];
    const float4* c4 = (const float4*)scale;
#pragma unroll
    for (int k = 0; k < 4; ++k) {
        float4 cv = c4[k];
        c[k].x = fminf(fmaxf(cv.x, 1e-6f), 1e6f);
        c[k].y = fminf(fmaxf(cv.y, 1e-6f), 1e6f);
        c[k].z = fminf(fmaxf(cv.z, 1e-6f), 1e6f);
        c[k].w = fminf(fmaxf(cv.w, 1e-6f), 1e6f);
    }

    // y side: 4 points = 12 contiguous floats (16B aligned)
    const float4* yv = (const float4*)(y + ((size_t)b * kNY + j0) * 3);
    float4 ya = yv[0], yb = yv[1], yc = yv[2];
    // x side: block-uniform address -> scalar loads
    const float4* xv = (const float4*)(x + ((size_t)b * kNX + i0) * 3);
    float4 xa = xv[0], xb = xv[1], xc = xv[2];

    const float yxx[4] = {ya.x, ya.w, yb.z, yc.y};
    const float yyy[4] = {ya.y, yb.x, yb.w, yc.z};
    const float yzz[4] = {ya.z, yb.y, yc.x, yc.w};
    const float xxx[4] = {xa.x, xa.w, xb.z, xc.y};
    const float xyy[4] = {xa.y, xb.x, xb.w, xc.z};
    const float xzz[4] = {xa.z, xb.y, xc.x, xc.w};

    // per-point stats: |p|^2 and sqrt(clip(sample . cscale))
    float sqx[4], scx[4], sqy[4], scy[4];
#pragma unroll
    for (int r = 0; r < 4; ++r) {
        sqx[r] = xxx[r] * xxx[r] + xyy[r] * xyy[r] + xzz[r] * xzz[r];
        sqy[r] = yxx[r] * yxx[r] + yyy[r] * yyy[r] + yzz[r] * yzz[r];
        const float4* a4 = (const float4*)(sx + ((size_t)b * kNX + i0 + r) * kF);
        const float4* b4 = (const float4*)(sy + ((size_t)b * kNY + j0 + r) * kF);
        float accx = 0.f, accy = 0.f;
#pragma unroll
        for (int k = 0; k < 4; ++k) {
            float4 av = a4[k], bv = b4[k], cv = c[k];
            accx += av.x * cv.x; accx += av.y * cv.y;
            accx += av.z * cv.z; accx += av.w * cv.w;
            accy += bv.x * cv.x; accy += bv.y * cv.y;
            accy += bv.z * cv.z; accy += bv.w * cv.w;
        }
        scx[r] = __builtin_amdgcn_sqrtf(fminf(fmaxf(accx, 1e-10f), 1e6f));
        scy[r] = __builtin_amdgcn_sqrtf(fminf(fmaxf(accy, 1e-10f), 1e6f));
    }

    // 4x4 tile: d = clip(|x|^2+|y|^2-2x.y), out = s/(s+d), s = scx*scy
    size_t obase = ((size_t)b * kNX + i0) * (size_t)kNY + j0;
#pragma unroll
    for (int r = 0; r < 4; ++r) {
        float4 o;
        float* op = (float*)&o;
#pragma unroll
        for (int k = 0; k < 4; ++k) {
            float dot = xxx[r] * yxx[k] + xyy[r] * yyy[k] + xzz[r] * yzz[k];
            float d = fmaf(-2.f, dot, sqx[r] + sqy[k]);
            d = fminf(fmaxf(d, 1e-10f), 1e6f);
            float s = fmaxf(scx[r] * scy[k], 1e-5f);
            op[k] = s * __builtin_amdgcn_rcpf(s + d);
        }
        *(float4*)(out + obase + (size_t)r * kNY) = o;
    }
}

extern "C" void kernel_launch(void* const* d_in, const int* in_sizes, int n_in,
                              void* d_out, int out_size, void* d_ws, size_t ws_size,
                              hipStream_t stream) {
    const float* x     = (const float*)d_in[0];
    const float* y     = (const float*)d_in[1];
    const float* sx    = (const float*)d_in[2];
    const float* sy    = (const float*)d_in[3];
    const float* scale = (const float*)d_in[4];
    float* out = (float*)d_out;

    const int main_blocks = (kB * kNX * kNY / 16) / 256;    // 16384
    cauchy_fused_kernel<<<main_blocks, 256, 0, stream>>>(
        x, y, sx, sy, scale, out);
}

// Round 4
// 263.007 us; speedup vs baseline: 1.4060x; 1.4060x over previous
//
#include <hip/hip_runtime.h>

// BatchedCauchyKernel3d: out[b,i,j] = 1 / (1 + d/sqrt(scx[b,i]*scy[b,j]))
// d = clip(|x_i|^2 + |y_j|^2 - 2 x_i.y_j, 1e-10, 1e6)
// scx = clip(sample_x . clip(scale,1e-6,1e6), 1e-10, 1e6); likewise scy.
// Identities:
//   1/(1+d/s) == s/(s+d)                       -> one rcp per element
//   sqrt(clip(scx*scy,1e-10,1e12)) == max(sqrt(scx)*sqrt(scy), 1e-5)
// Structure (R4): two-pass (stats pre-pass ~4us, then main) — R3 proved
// per-block stats recompute costs ~100us. Main is PERSISTENT: 2048 blocks
// (8/CU), each loops 8 tiles (4 batches x 2 row-halves) — kills the
// block-cold-start latency that held main at ~69us vs its 42us write floor.

constexpr int kB  = 4;
constexpr int kNX = 4096;
constexpr int kNY = 4096;
constexpr int kF  = 16;

// ---------------- pre-pass: per-point (|p|^2, sqrt(clipped scale-dot)) ------
__global__ __launch_bounds__(256) void row_stats_kernel(
    const float* __restrict__ x, const float* __restrict__ y,
    const float* __restrict__ sx, const float* __restrict__ sy,
    const float* __restrict__ scale,
    float2* __restrict__ rx, float2* __restrict__ ry, int nper)
{
    int t = blockIdx.x * blockDim.x + threadIdx.x;
    if (t >= 2 * nper) return;
    const float* pts; const float* smp; float2* dst; int idx;
    if (t < nper) { pts = x; smp = sx; dst = rx; idx = t; }
    else          { pts = y; smp = sy; dst = ry; idx = t - nper; }

    const float* p = pts + (size_t)idx * 3;
    float sq = p[0] * p[0] + p[1] * p[1] + p[2] * p[2];

    const float4* s4 = (const float4*)(smp + (size_t)idx * kF);
    const float4* c4 = (const float4*)scale;
    float acc = 0.f;
#pragma unroll
    for (int k = 0; k < kF / 4; ++k) {
        float4 sv = s4[k];
        float4 cv = c4[k];
        acc += sv.x * fminf(fmaxf(cv.x, 1e-6f), 1e6f);
        acc += sv.y * fminf(fmaxf(cv.y, 1e-6f), 1e6f);
        acc += sv.z * fminf(fmaxf(cv.z, 1e-6f), 1e6f);
        acc += sv.w * fminf(fmaxf(cv.w, 1e-6f), 1e6f);
    }
    float sc = fminf(fmaxf(acc, 1e-10f), 1e6f);
    dst[idx] = make_float2(sq, __builtin_amdgcn_sqrtf(sc));
}

// ---------------- main: persistent, 8 tiles of 4x4 per thread ---------------
// hw block (2048): jc = (hw&3)*256+tid -> j0 (loop-invariant, coalesced);
// qrow = hw>>2 (block-uniform -> x side is SALU/s_load). Tile loop:
// bb = batch (y-side loads hoisted), h = row-half (i0 = (h*512+qrow)*4).
__global__ __launch_bounds__(256) void cauchy_main_kernel(
    const float* __restrict__ x, const float* __restrict__ y,
    const float2* __restrict__ rx, const float2* __restrict__ ry,
    float* __restrict__ out)
{
    const int hw   = blockIdx.x;                      // 0..2047
    const int jc   = ((hw & 3) << 8) | threadIdx.x;   // 0..1023
    const int j0   = jc << 2;
    const int qrow = hw >> 2;                         // 0..511, block-uniform

#pragma unroll 1
    for (int bb = 0; bb < kB; ++bb) {
        // y side for (bb, j0): 12 contiguous floats + 4 float2 stats
        const float4* yv = (const float4*)(y + ((size_t)bb * kNY + j0) * 3);
        float4 ya = yv[0], yb = yv[1], yc = yv[2];
        const float4* ryv = (const float4*)(ry + (size_t)bb * kNY + j0);
        float4 r01 = ryv[0], r23 = ryv[1];

        const float yxx[4] = {ya.x, ya.w, yb.z, yc.y};
        const float yyy[4] = {ya.y, yb.x, yb.w, yc.z};
        const float yzz[4] = {ya.z, yb.y, yc.x, yc.w};
        const float sqy[4] = {r01.x, r01.z, r23.x, r23.z};
        const float scy[4] = {r01.y, r01.w, r23.y, r23.w};

#pragma unroll
        for (int h = 0; h < 2; ++h) {
            const int i0 = ((h << 9) | qrow) << 2;    // block-uniform

            const float4* xv = (const float4*)(x + ((size_t)bb * kNX + i0) * 3);
            float4 xa = xv[0], xb = xv[1], xc = xv[2];
            const float4* rxv = (const float4*)(rx + (size_t)bb * kNX + i0);
            float4 q01 = rxv[0], q23 = rxv[1];

            const float xxx[4] = {xa.x, xa.w, xb.z, xc.y};
            const float xyy[4] = {xa.y, xb.x, xb.w, xc.z};
            const float xzz[4] = {xa.z, xb.y, xc.x, xc.w};
            const float sqx[4] = {q01.x, q01.z, q23.x, q23.z};
            const float scx[4] = {q01.y, q01.w, q23.y, q23.w};

            size_t obase = ((size_t)bb * kNX + i0) * (size_t)kNY + j0;
#pragma unroll
            for (int r = 0; r < 4; ++r) {
                float4 o;
                float* op = (float*)&o;
#pragma unroll
                for (int k = 0; k < 4; ++k) {
                    float dot = xxx[r] * yxx[k] + xyy[r] * yyy[k] + xzz[r] * yzz[k];
                    float d = fmaf(-2.f, dot, sqx[r] + sqy[k]);
                    d = fminf(fmaxf(d, 1e-10f), 1e6f);
                    float s = fmaxf(scx[r] * scy[k], 1e-5f);
                    op[k] = s * __builtin_amdgcn_rcpf(s + d);
                }
                *(float4*)(out + obase + (size_t)r * kNY) = o;
            }
        }
    }
}

// ---------------- fallback (ws too small): fully fused, correct -------------
__global__ __launch_bounds__(256) void cauchy_fallback_kernel(
    const float* __restrict__ x, const float* __restrict__ y,
    const float* __restrict__ sx, const float* __restrict__ sy,
    const float* __restrict__ scale, float* __restrict__ out)
{
    const int t = blockIdx.x * 256 + threadIdx.x;
    const int jc = t & (kNY / 4 - 1);
    const int rowtile = t >> 10;
    const int b  = rowtile >> 10;
    const int i0 = (rowtile & (kNX / 4 - 1)) << 2;
    const int j0 = jc << 2;

    float4 c[4];
    const float4* c4 = (const float4*)scale;
#pragma unroll
    for (int k = 0; k < 4; ++k) {
        float4 cv = c4[k];
        c[k].x = fminf(fmaxf(cv.x, 1e-6f), 1e6f);
        c[k].y = fminf(fmaxf(cv.y, 1e-6f), 1e6f);
        c[k].z = fminf(fmaxf(cv.z, 1e-6f), 1e6f);
        c[k].w = fminf(fmaxf(cv.w, 1e-6f), 1e6f);
    }

    const float4* yv = (const float4*)(y + ((size_t)b * kNY + j0) * 3);
    float4 ya = yv[0], yb = yv[1], yc = yv[2];
    const float4* xv = (const float4*)(x + ((size_t)b * kNX + i0) * 3);
    float4 xa = xv[0], xb = xv[1], xc = xv[2];

    const float yxx[4] = {ya.x, ya.w, yb.z, yc.y};
    const float yyy[4] = {ya.y, yb.x, yb.w, yc.z};
    const float yzz[4] = {ya.z, yb.y, yc.x, yc.w};
    const float xxx[4] = {xa.x, xa.w, xb.z, xc.y};
    const float xyy[4] = {xa.y, xb.x, xb.w, xc.z};
    const float xzz[4] = {xa.z, xb.y, xc.x, xc.w};

    float sqx[4], scx[4], sqy[4], scy[4];
#pragma unroll
    for (int r = 0; r < 4; ++r) {
        sqx[r] = xxx[r] * xxx[r] + xyy[r] * xyy[r] + xzz[r] * xzz[r];
        sqy[r] = yxx[r] * yxx[r] + yyy[r] * yyy[r] + yzz[r] * yzz[r];
        const float4* a4 = (const float4*)(sx + ((size_t)b * kNX + i0 + r) * kF);
        const float4* b4 = (const float4*)(sy + ((size_t)b * kNY + j0 + r) * kF);
        float accx = 0.f, accy = 0.f;
#pragma unroll
        for (int k = 0; k < 4; ++k) {
            float4 av = a4[k], bv = b4[k], cv = c[k];
            accx += av.x * cv.x + av.y * cv.y + av.z * cv.z + av.w * cv.w;
            accy += bv.x * cv.x + bv.y * cv.y + bv.z * cv.z + bv.w * cv.w;
        }
        scx[r] = __builtin_amdgcn_sqrtf(fminf(fmaxf(accx, 1e-10f), 1e6f));
        scy[r] = __builtin_amdgcn_sqrtf(fminf(fmaxf(accy, 1e-10f), 1e6f));
    }

    size_t obase = ((size_t)b * kNX + i0) * (size_t)kNY + j0;
#pragma unroll
    for (int r = 0; r < 4; ++r) {
        float4 o;
        float* op = (float*)&o;
#pragma unroll
        for (int k = 0; k < 4; ++k) {
            float dot = xxx[r] * yxx[k] + xyy[r] * yyy[k] + xzz[r] * yzz[k];
            float d = fmaf(-2.f, dot, sqx[r] + sqy[k]);
            d = fminf(fmaxf(d, 1e-10f), 1e6f);
            float s = fmaxf(scx[r] * scy[k], 1e-5f);
            op[k] = s * __builtin_amdgcn_rcpf(s + d);
        }
        *(float4*)(out + obase + (size_t)r * kNY) = o;
    }
}

extern "C" void kernel_launch(void* const* d_in, const int* in_sizes, int n_in,
                              void* d_out, int out_size, void* d_ws, size_t ws_size,
                              hipStream_t stream) {
    const float* x     = (const float*)d_in[0];
    const float* y     = (const float*)d_in[1];
    const float* sx    = (const float*)d_in[2];
    const float* sy    = (const float*)d_in[3];
    const float* scale = (const float*)d_in[4];
    float* out = (float*)d_out;

    const int nper = kB * kNX;                              // 16384 points/side
    const size_t need = (size_t)2 * nper * sizeof(float2);  // 256 KiB

    if (ws_size >= need) {
        float2* rx = (float2*)d_ws;
        float2* ry = rx + nper;
        row_stats_kernel<<<(2 * nper + 255) / 256, 256, 0, stream>>>(
            x, y, sx, sy, scale, rx, ry, nper);
        cauchy_main_kernel<<<2048, 256, 0, stream>>>(x, y, rx, ry, out);
    } else {
        const int fb_blocks = (kB * kNX * kNY / 16) / 256;  // 16384
        cauchy_fallback_kernel<<<fb_blocks, 256, 0, stream>>>(
            x, y, sx, sy, scale, out);
    }
}